// Round 4
// baseline (276.744 us; speedup 1.0000x reference)
//
#include <hip/hip_runtime.h>
#include <stdint.h>

// out[b,s,u] = (LN(x) @ ternary(W)) * mean|W|   (reference's gamma absmax cancels)
// Fused pipeline: per-ROW activation scales (block-local when block owns whole
// rows), ternary weights exact in i8, i32 MFMA accumulation, scales in epilogue.
// Block = 128 rows x full N: LN+quant -> 128KiB LDS i8 tile, then barrier-free
// GEMM with A from LDS and B direct from L2 in MFMA-fragment order.
// x: (4,8192,1024) fp32 -> M=32768, K=1024, N=1024, out fp32.

#define M_ROWS 32768
#define KDIM 1024
#define NDIM 1024

typedef int v4i  __attribute__((ext_vector_type(4)));
typedef int v16i __attribute__((ext_vector_type(16)));

// ---------------- kernel 1: |w| partial sums ----------------
__global__ __launch_bounds__(256) void absum_k(const float* __restrict__ w,
                                               float* __restrict__ partials) {
    int idx = blockIdx.x * 256 + threadIdx.x;
    float4 v = ((const float4*)w)[idx];
    float s = fabsf(v.x) + fabsf(v.y) + fabsf(v.z) + fabsf(v.w);
    #pragma unroll
    for (int o = 32; o; o >>= 1) s += __shfl_xor(s, o);
    __shared__ float p[4];
    if ((threadIdx.x & 63) == 0) p[threadIdx.x >> 6] = s;
    __syncthreads();
    if (threadIdx.x == 0) partials[blockIdx.x] = p[0] + p[1] + p[2] + p[3];
}

// ---------------- kernel 2: ternarize -> wqB in MFMA-fragment order -------------
// B[n][k] stored at (n>>5)*32768 + (k>>5)*1024 + (((k>>4)&1)*32 + (n&31))*16 + (k&15)
// so a 32x32x32-i8 B fragment load is wqB[nt*32768 + kc*1024 + lane*16] (coalesced).
__global__ __launch_bounds__(256) void quant_k(const float* __restrict__ w,
                                               const float* __restrict__ partials,
                                               char* __restrict__ wqB,
                                               float* __restrict__ wsum) {
    int t = threadIdx.x;
    float s = partials[t] + partials[t + 256] + partials[t + 512] + partials[t + 768];
    #pragma unroll
    for (int o = 32; o; o >>= 1) s += __shfl_xor(s, o);
    __shared__ float ps[4];
    if ((t & 63) == 0) ps[t >> 6] = s;
    __syncthreads();
    float total = ps[0] + ps[1] + ps[2] + ps[3];
    if (blockIdx.x == 0 && t == 0) wsum[0] = total;
    float beta = total * (1.0f / 1048576.0f);
    float inv  = 1.0f / (beta + 1e-5f);

    __shared__ char sT[64 * 80];           // [n][k], stride 80 (16B-aligned rows)
    int k0 = (blockIdx.x >> 4) * 64, n0 = (blockIdx.x & 15) * 64;
    int n_l = t & 63;
    #pragma unroll
    for (int r = 0; r < 16; ++r) {
        int k_l = (t >> 6) * 16 + r;
        float q = rintf(w[(size_t)(k0 + k_l) * NDIM + n0 + n_l] * inv);
        q = fminf(1.0f, fmaxf(-1.0f, q));
        sT[n_l * 80 + k_l] = (char)(int)q;
    }
    __syncthreads();
    int nn = t & 63, c = t >> 6;           // c: which 16B k-chunk of this n-row
    v4i val = *(const v4i*)&sT[nn * 80 + c * 16];
    int n = n0 + nn, k = k0 + c * 16;
    size_t off = (size_t)(n >> 5) * 32768 + (size_t)(k >> 5) * 1024
               + (size_t)((((k >> 4) & 1) * 32 + (n & 31)) * 16);
    *(v4i*)&wqB[off] = val;
}

// ---------------- kernel 3: fused LN + per-row i8 quant + GEMM ------------------
// 256 blocks (1/CU) x 512 threads (8 waves, 2/SIMD). Phase 1: wave w LNs rows
// w*16..+15 into swizzled sA (chunk c of row r stored at position c^(r&7) in its
// 8-chunk group -> b128 reads stay 2-way/free). One barrier. Phase 2: waves in
// 2x4 (wm x wn), each 64m x 64n per bn-iter via 2x2 of 32x32x32 i8 MFMA; B frags
// are single coalesced dwordx4 loads from L2-resident wqB. No barriers in loop.
__global__ __launch_bounds__(512) void fused_k(const float* __restrict__ x,
                                               const float* __restrict__ g,
                                               const float* __restrict__ bia,
                                               const char* __restrict__ wqB,
                                               const float* __restrict__ wsum,
                                               float* __restrict__ out) {
    __shared__ char  sA[128 * 1024];
    __shared__ float sRS[128];
    int tid = threadIdx.x;
    int w = tid >> 6, lane = tid & 63;
    int bm0 = blockIdx.x * 128;

    float4 gg[4], bb[4];
    #pragma unroll
    for (int j = 0; j < 4; ++j) {
        gg[j] = ((const float4*)g)[lane + 64 * j];
        bb[j] = ((const float4*)bia)[lane + 64 * j];
    }

    #pragma unroll 2
    for (int rr = 0; rr < 16; ++rr) {
        int row = w * 16 + rr;
        const float4* xr = (const float4*)(x + (size_t)(bm0 + row) * KDIM);
        float4 v[4];
        #pragma unroll
        for (int j = 0; j < 4; ++j) v[j] = xr[lane + 64 * j];
        float s = 0.f, ss = 0.f;
        #pragma unroll
        for (int j = 0; j < 4; ++j) {
            s  += v[j].x + v[j].y + v[j].z + v[j].w;
            ss += v[j].x * v[j].x + v[j].y * v[j].y + v[j].z * v[j].z + v[j].w * v[j].w;
        }
        #pragma unroll
        for (int o = 32; o; o >>= 1) { s += __shfl_xor(s, o); ss += __shfl_xor(ss, o); }
        float mu  = s * (1.0f / 1024.0f);
        float var = ss * (1.0f / 1024.0f) - mu * mu;
        float rs  = rsqrtf(var + 1e-3f);    // keras LN eps
        float xn[16];
        float mx = 0.f;
        #pragma unroll
        for (int j = 0; j < 4; ++j) {
            xn[4*j+0] = (v[j].x - mu) * rs * gg[j].x + bb[j].x;
            xn[4*j+1] = (v[j].y - mu) * rs * gg[j].y + bb[j].y;
            xn[4*j+2] = (v[j].z - mu) * rs * gg[j].z + bb[j].z;
            xn[4*j+3] = (v[j].w - mu) * rs * gg[j].w + bb[j].w;
            #pragma unroll
            for (int e = 0; e < 4; ++e) mx = fmaxf(mx, fabsf(xn[4*j+e]));
        }
        #pragma unroll
        for (int o = 32; o; o >>= 1) mx = fmaxf(mx, __shfl_xor(mx, o));
        mx = fmaxf(mx, 1e-20f);
        if (lane == 0) sRS[row] = mx * (1.0f / 127.0f);
        float inv = 127.0f / mx;
        int sw = row & 7;
        #pragma unroll
        for (int j = 0; j < 4; ++j) {
            char4 c;
            c.x = (char)(int)rintf(xn[4*j+0] * inv);
            c.y = (char)(int)rintf(xn[4*j+1] * inv);
            c.z = (char)(int)rintf(xn[4*j+2] * inv);
            c.w = (char)(int)rintf(xn[4*j+3] * inv);
            int chunk = (lane >> 2) + 16 * j;           // 16B chunk index in row
            *(char4*)&sA[row * 1024 + ((chunk ^ sw) << 4) + ((lane & 3) << 2)] = c;
        }
    }
    __syncthreads();

    int l31 = lane & 31, half = lane >> 5;
    int wm = w & 1, wn = w >> 1;            // 2 x 4 wave grid
    float beta = wsum[0] * (1.0f / 1048576.0f);

    for (int bn = 0; bn < 4; ++bn) {
        int n0 = bn * 256 + wn * 64;        // this wave's 64-col base
        const char* bp = wqB + (size_t)(n0 >> 5) * 32768 + lane * 16;
        v16i acc[2][2] = {};
        #pragma unroll 4
        for (int kk = 0; kk < 32; ++kk) {
            int c16 = kk * 2 + half;
            v4i af[2], bf[2];
            #pragma unroll
            for (int i = 0; i < 2; ++i) {
                int m = wm * 64 + i * 32 + l31;
                af[i] = *(const v4i*)&sA[m * 1024 + ((c16 ^ (m & 7)) << 4)];
            }
            bf[0] = *(const v4i*)(bp + kk * 1024);
            bf[1] = *(const v4i*)(bp + 32768 + kk * 1024);
            #pragma unroll
            for (int i = 0; i < 2; ++i)
                #pragma unroll
                for (int j = 0; j < 2; ++j)
                    acc[i][j] = __builtin_amdgcn_mfma_i32_32x32x32_i8(af[i], bf[j], acc[i][j], 0, 0, 0);
        }
        #pragma unroll
        for (int i = 0; i < 2; ++i) {
            #pragma unroll
            for (int r = 0; r < 16; ++r) {
                // C/D 32x32: col = lane&31, row = (r&3) + 8*(r>>2) + 4*(lane>>5)
                int ml = wm * 64 + i * 32 + (r & 3) + 8 * (r >> 2) + 4 * half;
                float sc = sRS[ml] * beta;
                #pragma unroll
                for (int j = 0; j < 2; ++j) {
                    int nc = n0 + j * 32 + l31;
                    out[(size_t)(bm0 + ml) * NDIM + nc] = (float)acc[i][j][r] * sc;
                }
            }
        }
    }
}

extern "C" void kernel_launch(void* const* d_in, const int* in_sizes, int n_in,
                              void* d_out, int out_size, void* d_ws, size_t ws_size,
                              hipStream_t stream) {
    const float* x        = (const float*)d_in[0];   // 4*8192*1024
    const float* weight   = (const float*)d_in[1];   // 1024*1024
    const float* ln_gamma = (const float*)d_in[2];   // 1024
    const float* ln_beta  = (const float*)d_in[3];   // 1024
    float* out = (float*)d_out;

    // ws layout: [0,4) wsum | [4K,8K) partials(1024 f32) | [256K, 256K+1M) wqB i8
    float* wsum     = (float*)d_ws;
    float* partials = (float*)((char*)d_ws + 4096);
    char*  wqB      = (char*)d_ws + (1u << 18);

    absum_k<<<1024, 256, 0, stream>>>(weight, partials);
    quant_k<<<256, 256, 0, stream>>>(weight, partials, wqB, wsum);
    fused_k<<<M_ROWS / 128, 512, 0, stream>>>(x, ln_gamma, ln_beta, wqB, wsum, out);
}